// Round 8
// baseline (447.972 us; speedup 1.0000x reference)
//
#include <hip/hip_runtime.h>

#define LROW    2904
#define PERIOD  24
#define CYC     121          // LROW / PERIOD (odd -> median = 0-indexed rank 60)
#define NT      256
#define NF      207
#define NB      64
#define NROWS   13248        // NB * NF
#define CHUNK   (NROWS / 8)
#define LTILE   24
#define NLT     (LROW / LTILE)   // 121
#define K2GRID  (NB * NLT)       // 7744 = 8 * 968
#define K2CHUNK (K2GRID / 8)
#define CSTR    133          // padded col stride: bank = (5p+c)%32 -> conflict-free
#define TD      64           // transpose tile
#define WSTAB   (48 * NB * NF)   // 635904 floats: medians+Wtab table

__device__ __forceinline__ int clampi(int i) {
    return i < 0 ? 0 : (i >= LROW ? LROW - 1 : i);
}

// 16-bit absolute fixed-point key: grid 2^-12, range [-8, 8). Monotone.
__device__ __forceinline__ unsigned quantk(float d) {
    int ki = (int)fmaf(d, 4096.f, 32768.f);
    ki = ki < 0 ? 0 : (ki > 65535 ? 65535 : ki);
    return (unsigned)ki;
}
__device__ __forceinline__ float reconk(unsigned pref) {
    return ((float)(int)pref - 32767.5f) * (1.f / 4096.f);
}

__device__ __forceinline__ float ws_edge(int l, const float* lmed) {
    float w = 0.f;
    #pragma unroll
    for (int j = -6; j <= 6; ++j) {
        int idx = clampi(l + j);
        int ph = (idx < PERIOD) ? idx : idx - 2880;
        w += lmed[ph];
    }
    return w;
}

// Two interleaved ballot radix selects of rank 60 among 121 16-bit keys
// (2 keys/lane; dead k1 lanes hold 0xFFFFFFFF -> never match a valid prefix).
__device__ __forceinline__ void sel60x2(unsigned a0, unsigned a1,
                                        unsigned b0, unsigned b1,
                                        unsigned& prefA, unsigned& prefB) {
    int actA = __shfl(121, 0);
    int actB = actA;
    int rA = 60, rB = 60;
    unsigned pA = 0, pB = 0;
    #pragma unroll
    for (int bit = 15; bit >= 0; --bit) {
        unsigned wA = (pA << 1) | 1u;
        unsigned wB = (pB << 1) | 1u;
        unsigned long long mA0 = __ballot((a0 >> bit) == wA);
        unsigned long long mA1 = __ballot((a1 >> bit) == wA);
        unsigned long long mB0 = __ballot((b0 >> bit) == wB);
        unsigned long long mB1 = __ballot((b1 >> bit) == wB);
        int onesA = __popcll(mA0) + __popcll(mA1);
        int onesB = __popcll(mB0) + __popcll(mB1);
        int zA = actA - onesA, zB = actB - onesB;
        bool tA = (rA >= zA), tB = (rB >= zB);
        pA = tA ? wA : wA - 1u;  pB = tB ? wB : wB - 1u;
        rA = tA ? rA - zA : rA;  rB = tB ? rB - zB : rB;
        actA = tA ? onesA : zA;  actB = tB ? onesB : zB;
    }
    prefA = pA; prefB = pB;
}

// ============ Kernel 0: transpose x[B,L,F] -> xT[B*F][L] ===================
__global__ __launch_bounds__(256) void transpose_k(const float* __restrict__ x,
                                                   float* __restrict__ xT) {
    __shared__ float tile[TD][TD + 1];
    const int f0 = blockIdx.x * TD;
    const int l0 = blockIdx.y * TD;
    const int b  = blockIdx.z;
    const int t  = threadIdx.x;
    const int tx = t & 63, ty = t >> 6;
    const int lmax = min(TD, LROW - l0);   // 64 or 24
    const int fmax = min(TD, NF - f0);     // 64 or 15
    const float* xb = x + (size_t)b * (LROW * NF);
    for (int i = ty; i < lmax; i += 4)
        if (tx < fmax) tile[i][tx] = xb[(size_t)(l0 + i) * NF + f0 + tx];
    __syncthreads();
    float* xTb = xT + (size_t)b * NF * LROW;
    for (int i = ty; i < fmax; i += 4)
        if (tx < lmax) xTb[(size_t)(f0 + i) * LROW + l0 + tx] = tile[tx][i];
}

// ============ Kernel 1: medians + window-sum table =========================
template <bool TR>
__global__ __launch_bounds__(NT, 6) void stl_medians(const float* __restrict__ xin,
                                                     float* __restrict__ ws) {
    __shared__ float At[PERIOD][CSTR];    // phase-major input
    __shared__ float SAt[PERIOD][CSTR];   // phase-major window-13 clamped sum
    __shared__ float lmedA[PERIOD];
    __shared__ float lmedB[PERIOD];
    __shared__ float Wtab[PERIOD];

    const int d   = blockIdx.x;
    const int row = (d & 7) * CHUNK + (d >> 3);    // bijective XCD swizzle
    const int b = row / NF;
    const int f = row - b * NF;
    const int t = threadIdx.x;

    if (TR) {
        // contiguous float4 from xT row (row id == b*NF+f == row)
        const float4* src4 = (const float4*)(xin + (size_t)row * LROW);
        for (int i = t; i < LROW / 4; i += NT) {
            float4 v = src4[i];
            int l = i * 4;
            int c = l / PERIOD;
            int p = l - c * PERIOD;      // in {0,4,...,20}: all 4 share c
            At[p][c]     = v.x;
            At[p + 1][c] = v.y;
            At[p + 2][c] = v.z;
            At[p + 3][c] = v.w;
        }
    } else {
        const size_t rowbase = (size_t)b * (LROW * NF) + (size_t)f;
        int l = t, c = t / PERIOD, p = t - c * PERIOD;
        while (l < LROW) {
            At[p][c] = xin[rowbase + (size_t)l * NF];
            l += NT; p += 16; c += 10;
            if (p >= PERIOD) { p -= PERIOD; ++c; }
        }
    }
    __syncthreads();

    // ---- SAt: 242 threads, 2 half-period sliding segments per cycle column
    if (t < 242) {
        const int h  = (t >= 121) ? 1 : 0;
        const int c  = t - 121 * h;
        const int pb = 12 * h;
        const int l0 = c * PERIOD + pb;
        float s = 0.f;
        #pragma unroll
        for (int j = -6; j <= 6; ++j) {
            int lm = clampi(l0 + j);
            s += At[lm % PERIOD][lm / PERIOD];
        }
        SAt[pb][c] = s;
        #pragma unroll
        for (int q = 1; q < 12; ++q) {
            int la = clampi(l0 + q + 6), lr = clampi(l0 + q - 7);
            s += At[la % PERIOD][la / PERIOD] - At[lr % PERIOD][lr / PERIOD];
            SAt[pb + q][c] = s;
        }
    }
    __syncthreads();

    const int wid  = t >> 6;
    const int lane = t & 63;
    const int c1   = 64 + lane;
    const bool has1 = (c1 < CYC);

    // ================= iter 0: trend = SA/13; 3 select-pairs per wave ======
    #pragma unroll
    for (int pr = 0; pr < 3; ++pr) {
        const int pA = wid * 6 + pr * 2, pB = pA + 1;
        unsigned a0 = quantk(At[pA][lane] - SAt[pA][lane] * (1.f / 13.f));
        unsigned b0 = quantk(At[pB][lane] - SAt[pB][lane] * (1.f / 13.f));
        unsigned a1 = 0xFFFFFFFFu, b1 = 0xFFFFFFFFu;
        if (has1) {
            a1 = quantk(At[pA][c1] - SAt[pA][c1] * (1.f / 13.f));
            b1 = quantk(At[pB][c1] - SAt[pB][c1] * (1.f / 13.f));
        }
        unsigned prA, prB;
        sel60x2(a0, a1, b0, b1, prA, prB);
        if (lane == 0) { lmedA[pA] = reconk(prA); lmedA[pB] = reconk(prB); }
    }
    __syncthreads();
    if (t < PERIOD) {                       // Wtab0
        float w = 0.f;
        #pragma unroll
        for (int j = 0; j < 13; ++j) {
            int ph = t + j; if (ph >= PERIOD) ph -= PERIOD;
            w += lmedA[ph];
        }
        Wtab[t] = w;
    }
    __syncthreads();

    // ================= iter 1: only 12 edge phases re-select ===============
    #pragma unroll 1
    for (int rep = 0; rep < 2; ++rep) {
        const int j = (rep == 0) ? wid : (wid < 2 ? 4 + wid : 99);
        if (j > 5) continue;
        const int pA = j, pB = 18 + j;
        const float wA = Wtab[j + 18];
        const float wB = Wtab[j + 12];
        float wA0 = (lane == 0) ? ws_edge(pA, lmedA) : wA;
        unsigned a0 = quantk(At[pA][lane] - (SAt[pA][lane] - wA0) * (1.f / 13.f));
        unsigned b0 = quantk(At[pB][lane] - (SAt[pB][lane] - wB)  * (1.f / 13.f));
        unsigned a1 = 0xFFFFFFFFu, b1 = 0xFFFFFFFFu;
        if (has1) {
            float wB1 = (lane == 56) ? ws_edge(2880 + pB, lmedA) : wB;
            a1 = quantk(At[pA][c1] - (SAt[pA][c1] - wA)  * (1.f / 13.f));
            b1 = quantk(At[pB][c1] - (SAt[pB][c1] - wB1) * (1.f / 13.f));
        }
        unsigned prA, prB;
        sel60x2(a0, a1, b0, b1, prA, prB);
        if (lane == 0) { lmedB[pA] = reconk(prA); lmedB[pB] = reconk(prB); }
    }
    __syncthreads();
    if (t < PERIOD) {
        if (t >= 6 && t < 18)
            lmedB[t] = lmedA[t] + Wtab[t - 6] * (1.f / 13.f);
        float w = 0.f;
        #pragma unroll
        for (int j2 = 0; j2 < 13; ++j2) {
            int ph = t + j2; if (ph >= PERIOD) ph -= PERIOD;
            w += lmedB[ph];
        }
        Wtab[t] = w;                        // Wtab1
    }
    __syncthreads();

    if (t < 48) {
        int isW = (t >= 24);
        int p2  = t - (isW ? 24 : 0);
        ws[((size_t)b * 48 + t) * NF + f] = isW ? Wtab[p2] : lmedB[p2];
    }
}

// ============ Kernel 2: coalesced outputs (nontemporal stores) =============
__global__ __launch_bounds__(NT, 5) void stl_outputs(const float* __restrict__ x,
                                                     const float* __restrict__ ws,
                                                     float* __restrict__ out) {
    __shared__ float T[(LTILE + 12) * NF];

    const int d   = blockIdx.x;
    const int blk = (d & 7) * K2CHUNK + (d >> 3);
    const int b  = blk / NLT;
    const int kk = blk - b * NLT;
    const int l0 = kk * LTILE;
    const int t  = threadIdx.x;
    const float* xb = x + (size_t)b * (LROW * NF);

    if (kk != 0 && kk != NLT - 1) {
        const float2* s2 = (const float2*)(xb + (size_t)(l0 - 6) * NF);
        float2* t2 = (float2*)T;
        for (int i = t; i < (LTILE + 12) * NF / 2; i += NT) t2[i] = s2[i];
    } else {
        for (int i = t; i < (LTILE + 12) * NF; i += NT) {
            int lr = i / NF;
            int ff = i - lr * NF;
            T[i] = xb[(size_t)clampi(l0 - 6 + lr) * NF + ff];
        }
    }
    __syncthreads();

    if (t < NF) {
        float lm[PERIOD], wt[PERIOD];
        const float* wrow = ws + (size_t)b * 48 * NF + t;
        #pragma unroll
        for (int i = 0; i < PERIOD; ++i) lm[i] = wrow[i * NF];
        #pragma unroll
        for (int i = 0; i < PERIOD; ++i) wt[i] = wrow[(PERIOD + i) * NF];

        float s13 = 0.f;
        #pragma unroll
        for (int r = 0; r < 13; ++r) s13 += T[r * NF + t];

        const bool edgeLo = (kk == 0), edgeHi = (kk == NLT - 1);
        const size_t S = (size_t)NROWS * LROW;
        const size_t obase = (size_t)b * (LROW * NF) + (size_t)l0 * NF + (size_t)t;

        #pragma unroll
        for (int j = 0; j < LTILE; ++j) {
            float W = wt[(j + 18) % 24];
            if (edgeLo && j < 6) {
                float w = 0.f;
                #pragma unroll
                for (int jj = -6; jj <= 6; ++jj) { int m = j + jj; if (m < 0) m = 0; w += lm[m]; }
                W = w;
            }
            if (edgeHi && j >= 18) {
                float w = 0.f;
                #pragma unroll
                for (int jj = -6; jj <= 6; ++jj) { int m = j + jj; if (m > 23) m = 23; w += lm[m]; }
                W = w;
            }
            float tr = (s13 - W) * (1.f / 13.f);
            float se = lm[j];
            float re = T[(j + 6) * NF + t] - tr - se;
            size_t o = obase + (size_t)(j * NF);
            __builtin_nontemporal_store(tr, &out[o]);
            __builtin_nontemporal_store(se, &out[S + o]);
            __builtin_nontemporal_store(re, &out[2 * S + o]);
            if (j < LTILE - 1)
                s13 += T[(j + 13) * NF + t] - T[j * NF + t];
        }
    }
}

extern "C" void kernel_launch(void* const* d_in, const int* in_sizes, int n_in,
                              void* d_out, int out_size, void* d_ws, size_t ws_size,
                              hipStream_t stream) {
    const float* x = (const float*)d_in[0];
    float* out = (float*)d_out;
    float* wsTab = (float*)d_ws;                 // 2.55 MB table
    float* xT = wsTab + WSTAB;                   // 153.9 MB transposed input
    (void)in_sizes; (void)n_in; (void)out_size;

    const size_t need = (size_t)(WSTAB + (size_t)NROWS * LROW) * sizeof(float);
    if (ws_size >= need) {
        hipLaunchKernelGGL(transpose_k, dim3(4, 46, NB), dim3(256), 0, stream, x, xT);
        hipLaunchKernelGGL((stl_medians<true>), dim3(NROWS), dim3(NT), 0, stream,
                           xT, wsTab);
    } else {
        hipLaunchKernelGGL((stl_medians<false>), dim3(NROWS), dim3(NT), 0, stream,
                           x, wsTab);
    }
    hipLaunchKernelGGL(stl_outputs, dim3(K2GRID), dim3(NT), 0, stream, x, wsTab, out);
}

// Round 9
// 445.313 us; speedup vs baseline: 1.0060x; 1.0060x over previous
//
#include <hip/hip_runtime.h>

#define LROW    2904
#define PERIOD  24
#define CYC     121          // LROW / PERIOD (odd -> median = 0-indexed rank 60)
#define NT      256
#define NF      207
#define NB      64
#define NROWS   13248        // NB * NF
#define K1GRID  (NROWS / 4)  // 3312 blocks x 4 waves (1 row per wave)
#define K1CHUNK (K1GRID / 8) // 414
#define LTILE   24
#define NLT     121
#define K2GRID  (NB * NLT)   // 7744
#define K2CHUNK (K2GRID / 8)
#define TD      64
#define WSTAB   (48 * NB * NF)
#define R13     (1.f / 13.f)

__device__ __forceinline__ int clampi(int i) {
    return i < 0 ? 0 : (i >= LROW ? LROW - 1 : i);
}

// 16-bit absolute fixed-point key: grid 2^-12, range [-8, 8). Monotone.
__device__ __forceinline__ unsigned quantk(float d) {
    int ki = (int)fmaf(d, 4096.f, 32768.f);
    ki = ki < 0 ? 0 : (ki > 65535 ? 65535 : ki);
    return (unsigned)ki;
}
__device__ __forceinline__ float reconk(unsigned pref) {
    return ((float)(int)pref - 32767.5f) * (1.f / 4096.f);
}

// Two interleaved ballot radix selects of rank 60 among 121 16-bit keys
// (2 keys/lane; dead second-chunk lanes hold 0xFFFFFFFF -> can never match).
// bit-loop kept partially rolled: code size (18 inlined call sites) must stay
// under the 32KB shared I$. act/r/pref forced to VGPR via shfl-poison.
__device__ __forceinline__ void sel60x2(unsigned a0, unsigned a1,
                                        unsigned b0, unsigned b1,
                                        unsigned& prefA, unsigned& prefB) {
    int actA = __shfl(121, 0);
    int actB = actA;
    int rA = 60, rB = 60;
    unsigned pA = 0, pB = 0;
    #pragma unroll 2
    for (int bit = 15; bit >= 0; --bit) {
        unsigned wA = (pA << 1) | 1u;
        unsigned wB = (pB << 1) | 1u;
        unsigned long long mA0 = __ballot((a0 >> bit) == wA);
        unsigned long long mA1 = __ballot((a1 >> bit) == wA);
        unsigned long long mB0 = __ballot((b0 >> bit) == wB);
        unsigned long long mB1 = __ballot((b1 >> bit) == wB);
        int onesA = __popcll(mA0) + __popcll(mA1);
        int onesB = __popcll(mB0) + __popcll(mB1);
        int zA = actA - onesA, zB = actB - onesB;
        bool tA = (rA >= zA), tB = (rB >= zB);
        pA = tA ? wA : wA - 1u;  pB = tB ? wB : wB - 1u;
        rA = tA ? rA - zA : rA;  rB = tB ? rB - zB : rB;
        actA = tA ? onesA : zA;  actB = tB ? onesB : zB;
    }
    prefA = pA; prefB = pB;
}

// ============ Kernel 0: transpose x[B,L,F] -> xT[B*F][L] ===================
__global__ __launch_bounds__(256) void transpose_k(const float* __restrict__ x,
                                                   float* __restrict__ xT) {
    __shared__ float tile[TD][TD + 1];
    const int f0 = blockIdx.x * TD;
    const int l0 = blockIdx.y * TD;
    const int b  = blockIdx.z;
    const int t  = threadIdx.x;
    const int tx = t & 63, ty = t >> 6;
    const int lmax = min(TD, LROW - l0);   // 64 or 24 (both /4)
    const int fmax = min(TD, NF - f0);     // 64 or 15
    const float* xb = x + (size_t)b * (LROW * NF);
    for (int i = ty; i < lmax; i += 4)
        if (tx < fmax) tile[i][tx] = xb[(size_t)(l0 + i) * NF + f0 + tx];
    __syncthreads();
    float* xTb = xT + (size_t)b * NF * LROW;
    const int l4 = (t & 15) * 4;
    const int fi = t >> 4;
    #pragma unroll
    for (int ii = 0; ii < 4; ++ii) {
        int fl = fi + 16 * ii;
        if (fl < fmax && l4 < lmax) {
            float4 v;
            v.x = tile[l4 + 0][fl]; v.y = tile[l4 + 1][fl];
            v.z = tile[l4 + 2][fl]; v.w = tile[l4 + 3][fl];
            *(float4*)&xTb[(size_t)(f0 + fl) * LROW + l0 + l4] = v;
        }
    }
}

// ============ Kernel 1: one wave per row, zero barriers, zero LDS ==========
// Lane owns cycles c=lane (chunk A) and c=64+lane (chunk B): each is 24
// consecutive floats of the row. Sliding window sums via +-6 shfl'd halo.
__global__ __launch_bounds__(256) void stl_medians(const float* __restrict__ xT,
                                                   float* __restrict__ ws) {
    const int d    = blockIdx.x;
    const int blk  = (d & 7) * K1CHUNK + (d >> 3);   // bijective XCD swizzle
    const int wid  = threadIdx.x >> 6;
    const int lane = threadIdx.x & 63;
    const int row  = blk * 4 + wid;
    const int b = row / NF;
    const int f = row - b * NF;
    const float* xrow = xT + (size_t)row * LROW;

    // ---- load both chunks (float4, 96B per lane, contiguous per wave)
    float a[24], bch[24];
    {
        const float4* pa = (const float4*)(xrow + lane * 24);
        #pragma unroll
        for (int j = 0; j < 6; ++j) {
            float4 v = pa[j];
            a[4*j+0] = v.x; a[4*j+1] = v.y; a[4*j+2] = v.z; a[4*j+3] = v.w;
        }
        int c1 = 64 + lane; if (c1 > 120) c1 = 120;   // lanes>=57: dead, clamp
        const float4* pb = (const float4*)(xrow + c1 * 24);
        #pragma unroll
        for (int j = 0; j < 6; ++j) {
            float4 v = pb[j];
            bch[4*j+0] = v.x; bch[4*j+1] = v.y; bch[4*j+2] = v.z; bch[4*j+3] = v.w;
        }
    }

    // ---- +-6 halo via shuffles (row ends replicate-clamped)
    const int lp1 = (lane + 1) & 63, lm1 = (lane + 63) & 63;
    float pA[6], nA[6], pB[6], nB[6];
    #pragma unroll
    for (int j = 0; j < 6; ++j) {
        float v1 = __shfl(a[18 + j], lm1);
        pA[j] = (lane == 0) ? a[0] : v1;              // c=0: replicate A[0]
    }
    #pragma unroll
    for (int j = 0; j < 6; ++j) {
        float v1 = __shfl(a[j], lp1);
        float v2 = __shfl(bch[j], lp1);               // c=63 -> lane0's chunk B
        nA[j] = (lane == 63) ? v2 : v1;
    }
    #pragma unroll
    for (int j = 0; j < 6; ++j) {
        float v1 = __shfl(bch[18 + j], lm1);
        float v2 = __shfl(a[18 + j], lm1);            // c=64 -> lane63's chunk A
        pB[j] = (lane == 0) ? v2 : v1;
    }
    #pragma unroll
    for (int j = 0; j < 6; ++j) {
        float v1 = __shfl(bch[j], lp1);
        nB[j] = (lane == 56) ? bch[23] : v1;          // c=120: replicate A[2903]
    }

    // ---- d0[p] = A - MA13(A)  (sliding window sum, all registers)
    float d0a[24], d0b[24];
    {
        float s = pA[0]+pA[1]+pA[2]+pA[3]+pA[4]+pA[5]
                + a[0]+a[1]+a[2]+a[3]+a[4]+a[5]+a[6];
        d0a[0] = fmaf(s, -R13, a[0]);
        #pragma unroll
        for (int p = 1; p < 24; ++p) {
            float wout = (p <= 6) ? pA[p-1] : a[p-7];
            float win  = (p < 18) ? a[p+6] : nA[p-18];
            s += win - wout;
            d0a[p] = fmaf(s, -R13, a[p]);
        }
    }
    {
        float s = pB[0]+pB[1]+pB[2]+pB[3]+pB[4]+pB[5]
                + bch[0]+bch[1]+bch[2]+bch[3]+bch[4]+bch[5]+bch[6];
        d0b[0] = fmaf(s, -R13, bch[0]);
        #pragma unroll
        for (int p = 1; p < 24; ++p) {
            float wout = (p <= 6) ? pB[p-1] : bch[p-7];
            float win  = (p < 18) ? bch[p+6] : nB[p-18];
            s += win - wout;
            d0b[p] = fmaf(s, -R13, bch[p]);
        }
    }

    const bool deadB = (lane >= 57);

    // ---- iter 0: 24 selects (12 interleaved pairs), straight-line
    float med[24];
    #pragma unroll
    for (int pr = 0; pr < 12; ++pr) {
        unsigned a0 = quantk(d0a[2*pr]);
        unsigned a1 = deadB ? 0xFFFFFFFFu : quantk(d0b[2*pr]);
        unsigned b0 = quantk(d0a[2*pr+1]);
        unsigned b1 = deadB ? 0xFFFFFFFFu : quantk(d0b[2*pr+1]);
        unsigned prA, prB;
        sel60x2(a0, a1, b0, b1, prA, prB);
        med[2*pr]   = reconk(prA);
        med[2*pr+1] = reconk(prB);
    }

    // ---- Wtab0 (uniform, registers)
    float W[24];
    {
        float s = med[0]+med[1]+med[2]+med[3]+med[4]+med[5]+med[6]
                + med[7]+med[8]+med[9]+med[10]+med[11]+med[12];
        W[0] = s;
        #pragma unroll
        for (int q = 1; q < 24; ++q)
            W[q] = W[q-1] + med[(q + 12) % 24] - med[q-1];
    }

    // ---- edge window sums for phases 0..5 (c=0) and 18..23 (c=120)
    float welo[6], wehi[6];
    #pragma unroll
    for (int p = 0; p < 6; ++p) {
        float s = 0.f;
        #pragma unroll
        for (int j = -6; j <= 6; ++j) { int m = p + j; if (m < 0) m = 0; s += med[m]; }
        welo[p] = s;
    }
    #pragma unroll
    for (int p = 0; p < 6; ++p) {
        float s = 0.f;
        #pragma unroll
        for (int j = -6; j <= 6; ++j) { int m = 18 + p + j; if (m > 23) m = 23; s += med[m]; }
        wehi[p] = s;
    }

    // ---- iter 1: 12 edge phases re-select; interior 12 translate exactly
    float medB[24];
    #pragma unroll
    for (int j = 0; j < 6; ++j) {
        float WA  = W[j + 18] * R13;                   // (pA+18)%24, pA=j
        float WB  = W[j + 12] * R13;                   // (pB+18)%24, pB=18+j
        float wA0 = (lane == 0)  ? welo[j] * R13 : WA; // c=0 edge element
        float wB1 = (lane == 56) ? wehi[j] * R13 : WB; // c=120 edge element
        unsigned a0 = quantk(d0a[j] + wA0);
        unsigned a1 = deadB ? 0xFFFFFFFFu : quantk(d0b[j] + WA);
        unsigned b0 = quantk(d0a[18 + j] + WB);
        unsigned b1 = deadB ? 0xFFFFFFFFu : quantk(d0b[18 + j] + wB1);
        unsigned prA, prB;
        sel60x2(a0, a1, b0, b1, prA, prB);
        medB[j]      = reconk(prA);
        medB[18 + j] = reconk(prB);
    }
    #pragma unroll
    for (int p = 6; p < 18; ++p)
        medB[p] = med[p] + W[p - 6] * R13;

    // ---- Wtab1
    float W1[24];
    {
        float s = medB[0]+medB[1]+medB[2]+medB[3]+medB[4]+medB[5]+medB[6]
                + medB[7]+medB[8]+medB[9]+medB[10]+medB[11]+medB[12];
        W1[0] = s;
        #pragma unroll
        for (int q = 1; q < 24; ++q)
            W1[q] = W1[q-1] + medB[(q + 12) % 24] - medB[q-1];
    }

    // ---- distribute uniform values to lanes (static cndmask chain) & store
    float myv = medB[0];
    #pragma unroll
    for (int p = 1; p < 24; ++p) myv = (lane == p) ? medB[p] : myv;
    #pragma unroll
    for (int q = 0; q < 24; ++q) myv = (lane == 24 + q) ? W1[q] : myv;
    if (lane < 48)
        ws[((size_t)b * 48 + lane) * NF + f] = myv;
}

// ============ Kernel 2: coalesced outputs (nontemporal stores) =============
__global__ __launch_bounds__(NT, 5) void stl_outputs(const float* __restrict__ x,
                                                     const float* __restrict__ ws,
                                                     float* __restrict__ out) {
    __shared__ float T[(LTILE + 12) * NF];

    const int d   = blockIdx.x;
    const int blk = (d & 7) * K2CHUNK + (d >> 3);
    const int b  = blk / NLT;
    const int kk = blk - b * NLT;
    const int l0 = kk * LTILE;
    const int t  = threadIdx.x;
    const float* xb = x + (size_t)b * (LROW * NF);

    if (kk != 0 && kk != NLT - 1) {
        const float2* s2 = (const float2*)(xb + (size_t)(l0 - 6) * NF);
        float2* t2 = (float2*)T;
        for (int i = t; i < (LTILE + 12) * NF / 2; i += NT) t2[i] = s2[i];
    } else {
        for (int i = t; i < (LTILE + 12) * NF; i += NT) {
            int lr = i / NF;
            int ff = i - lr * NF;
            T[i] = xb[(size_t)clampi(l0 - 6 + lr) * NF + ff];
        }
    }
    __syncthreads();

    if (t < NF) {
        float lm[PERIOD], wt[PERIOD];
        const float* wrow = ws + (size_t)b * 48 * NF + t;
        #pragma unroll
        for (int i = 0; i < PERIOD; ++i) lm[i] = wrow[i * NF];
        #pragma unroll
        for (int i = 0; i < PERIOD; ++i) wt[i] = wrow[(PERIOD + i) * NF];

        float s13 = 0.f;
        #pragma unroll
        for (int r = 0; r < 13; ++r) s13 += T[r * NF + t];

        const bool edgeLo = (kk == 0), edgeHi = (kk == NLT - 1);
        const size_t S = (size_t)NROWS * LROW;
        const size_t obase = (size_t)b * (LROW * NF) + (size_t)l0 * NF + (size_t)t;

        #pragma unroll
        for (int j = 0; j < LTILE; ++j) {
            float W = wt[(j + 18) % 24];
            if (edgeLo && j < 6) {
                float w = 0.f;
                #pragma unroll
                for (int jj = -6; jj <= 6; ++jj) { int m = j + jj; if (m < 0) m = 0; w += lm[m]; }
                W = w;
            }
            if (edgeHi && j >= 18) {
                float w = 0.f;
                #pragma unroll
                for (int jj = -6; jj <= 6; ++jj) { int m = j + jj; if (m > 23) m = 23; w += lm[m]; }
                W = w;
            }
            float tr = (s13 - W) * (1.f / 13.f);
            float se = lm[j];
            float re = T[(j + 6) * NF + t] - tr - se;
            size_t o = obase + (size_t)(j * NF);
            __builtin_nontemporal_store(tr, &out[o]);
            __builtin_nontemporal_store(se, &out[S + o]);
            __builtin_nontemporal_store(re, &out[2 * S + o]);
            if (j < LTILE - 1)
                s13 += T[(j + 13) * NF + t] - T[j * NF + t];
        }
    }
}

extern "C" void kernel_launch(void* const* d_in, const int* in_sizes, int n_in,
                              void* d_out, int out_size, void* d_ws, size_t ws_size,
                              hipStream_t stream) {
    const float* x = (const float*)d_in[0];
    float* out = (float*)d_out;
    float* wsTab = (float*)d_ws;                 // 2.55 MB table
    float* xT = wsTab + WSTAB;                   // 153.9 MB transposed input
    (void)in_sizes; (void)n_in; (void)out_size; (void)ws_size;
    hipLaunchKernelGGL(transpose_k, dim3(4, 46, NB), dim3(256), 0, stream, x, xT);
    hipLaunchKernelGGL(stl_medians, dim3(K1GRID), dim3(256), 0, stream, xT, wsTab);
    hipLaunchKernelGGL(stl_outputs, dim3(K2GRID), dim3(NT), 0, stream, x, wsTab, out);
}